// Round 2
// baseline (3194.193 us; speedup 1.0000x reference)
//
#include <hip/hip_runtime.h>

#define HID 2048
#define BAT 512
#define SEQ 128
#define NCLS 10

typedef __attribute__((ext_vector_type(4))) float f32x4;
typedef __attribute__((ext_vector_type(8))) short s16x8;
typedef __attribute__((ext_vector_type(4))) unsigned short u16x4;

__device__ __forceinline__ float bf2f(unsigned short u) {
  union { unsigned int i; float f; } v;
  v.i = ((unsigned int)u) << 16;
  return v.f;
}
__device__ __forceinline__ unsigned short f2bf(float f) {
  union { float f; unsigned int i; } v;
  v.f = f;
  unsigned int u = v.i;
  return (unsigned short)((u + 0x7fffu + ((u >> 16) & 1u)) >> 16);
}

// fp32 -> bf16 conversion, 4 elems/thread
__global__ __launch_bounds__(256) void cvt_kernel(const float* __restrict__ src,
                                                  unsigned short* __restrict__ dst,
                                                  int n) {
  int i = (blockIdx.x * 256 + threadIdx.x) * 4;
  if (i + 3 < n) {
    f32x4 v = *(const f32x4*)(src + i);
    u16x4 o;
    o.x = f2bf(v.x);
    o.y = f2bf(v.y);
    o.z = f2bf(v.z);
    o.w = f2bf(v.w);
    *(u16x4*)(dst + i) = o;
  }
}

__device__ __forceinline__ void gload16(const void* g, void* l) {
  __builtin_amdgcn_global_load_lds(
      (const __attribute__((address_space(1))) unsigned int*)g,
      (__attribute__((address_space(3))) unsigned int*)l, 16, 0, 0);
}

// One recurrence step: hout[n][m] = tanh( sum_k W[m][k]*hin[n][k] + whx[m]*x[n][t] + bh[m] )
// W: [HID][HID] bf16 row-major (K-contiguous). hin/hout: [BAT][HID] bf16 (h transposed, K-contiguous).
// Tile: BM=64 (m = hidden-out), BN=64 (n = batch), BK=32. 256 threads = 4 waves as 2x2,
// each wave computes a 32x32 quadrant = 2x2 MFMA 16x16x32 fragments.
__global__ __launch_bounds__(256) void step_kernel(
    const unsigned short* __restrict__ W,
    const unsigned short* __restrict__ hin,
    unsigned short* __restrict__ hout,
    const float* __restrict__ whx,   // [HID]
    const float* __restrict__ bh,    // [HID]
    const float* __restrict__ x,     // [BAT][SEQ]
    int t) {
  __shared__ unsigned short At[64 * 32];  // [row][k] linear, row-major
  __shared__ unsigned short Bt[64 * 32];

  const int tid = threadIdx.x;
  const int wave = tid >> 6;
  const int lane = tid & 63;
  const int m0 = blockIdx.x * 64;
  const int n0 = blockIdx.y * 64;
  const int wm = wave >> 1;
  const int wn = wave & 1;

  // staging: each wave covers 16 rows (16 rows * 64 B/row = 1 KiB = 64 lanes * 16 B)
  const int srow = wave * 16 + (lane >> 2);
  const int scol = (lane & 3) * 8;  // element col within BK=32
  const unsigned short* gA = W + (size_t)(m0 + srow) * HID + scol;
  const unsigned short* gB = hin + (size_t)(n0 + srow) * HID + scol;
  unsigned short* lA = At + wave * 512;  // wave-uniform LDS base; lane*16B implicit
  unsigned short* lB = Bt + wave * 512;

  f32x4 acc[2][2] = {};
  const int fl = lane & 15;
  const int fk = (lane >> 4) * 8;

  for (int kk = 0; kk < HID; kk += 32) {
    gload16(gA + kk, lA);
    gload16(gB + kk, lB);
    __syncthreads();  // drains vmcnt (global_load_lds) per compiler semantics
    s16x8 a0 = *(const s16x8*)&At[(wm * 32 + fl) * 32 + fk];
    s16x8 a1 = *(const s16x8*)&At[(wm * 32 + 16 + fl) * 32 + fk];
    s16x8 b0 = *(const s16x8*)&Bt[(wn * 32 + fl) * 32 + fk];
    s16x8 b1 = *(const s16x8*)&Bt[(wn * 32 + 16 + fl) * 32 + fk];
    acc[0][0] = __builtin_amdgcn_mfma_f32_16x16x32_bf16(a0, b0, acc[0][0], 0, 0, 0);
    acc[0][1] = __builtin_amdgcn_mfma_f32_16x16x32_bf16(a0, b1, acc[0][1], 0, 0, 0);
    acc[1][0] = __builtin_amdgcn_mfma_f32_16x16x32_bf16(a1, b0, acc[1][0], 0, 0, 0);
    acc[1][1] = __builtin_amdgcn_mfma_f32_16x16x32_bf16(a1, b1, acc[1][1], 0, 0, 0);
    __syncthreads();  // WAR: protect LDS before next stage
  }

  // epilogue: C/D layout col = lane&15, row = (lane>>4)*4 + j  [m89/m91-verified]
  const int mbase = m0 + wm * 32;
  const int nbase = n0 + wn * 32;
#pragma unroll
  for (int mf = 0; mf < 2; ++mf) {
    const int mrow = mbase + mf * 16 + (lane >> 4) * 4;
    const f32x4 wx = *(const f32x4*)&whx[mrow];
    const f32x4 bb = *(const f32x4*)&bh[mrow];
#pragma unroll
    for (int nf = 0; nf < 2; ++nf) {
      const int ncol = nbase + nf * 16 + fl;
      const float xv = x[ncol * SEQ + t];
      u16x4 o;
#pragma unroll
      for (int j = 0; j < 4; ++j) {
        float z = acc[mf][nf][j] + wx[j] * xv + bb[j];
        o[j] = f2bf(tanhf(z));
      }
      *(u16x4*)&hout[(size_t)ncol * HID + mrow] = o;  // 8 B store, 4 consecutive m
    }
  }
}

// out[b][c] = sum_k wp[c][k] * h[k][b] + bp[c];  h stored as hT[b][k]
__global__ __launch_bounds__(256) void proj_kernel(const unsigned short* __restrict__ hT,
                                                   const float* __restrict__ wp,
                                                   const float* __restrict__ bp,
                                                   float* __restrict__ out) {
  const int b = blockIdx.x;
  const int wave = threadIdx.x >> 6;
  const int lane = threadIdx.x & 63;
  for (int c = wave; c < NCLS; c += 4) {
    float s = 0.f;
    for (int k = lane * 8; k < HID; k += 512) {
      s16x8 hv = *(const s16x8*)&hT[b * HID + k];
      f32x4 w0 = *(const f32x4*)&wp[c * HID + k];
      f32x4 w1 = *(const f32x4*)&wp[c * HID + k + 4];
      s += w0.x * bf2f((unsigned short)hv[0]) + w0.y * bf2f((unsigned short)hv[1]) +
           w0.z * bf2f((unsigned short)hv[2]) + w0.w * bf2f((unsigned short)hv[3]) +
           w1.x * bf2f((unsigned short)hv[4]) + w1.y * bf2f((unsigned short)hv[5]) +
           w1.z * bf2f((unsigned short)hv[6]) + w1.w * bf2f((unsigned short)hv[7]);
    }
#pragma unroll
    for (int off = 32; off > 0; off >>= 1) s += __shfl_down(s, off);
    if (lane == 0) out[b * NCLS + c] = s + bp[c];
  }
}

extern "C" void kernel_launch(void* const* d_in, const int* in_sizes, int n_in,
                              void* d_out, int out_size, void* d_ws, size_t ws_size,
                              hipStream_t stream) {
  (void)in_sizes; (void)n_in; (void)out_size; (void)ws_size;
  const float* x   = (const float*)d_in[0];  // [BAT][SEQ]
  const float* whx = (const float*)d_in[1];  // [HID][1]
  const float* whh = (const float*)d_in[2];  // [HID][HID]
  const float* bh  = (const float*)d_in[3];  // [HID][1]
  const float* wp  = (const float*)d_in[4];  // [NCLS][HID]
  const float* bp  = (const float*)d_in[5];  // [NCLS][1]
  float* out = (float*)d_out;                // [BAT][NCLS]

  unsigned short* Wb = (unsigned short*)d_ws;          // HID*HID bf16 = 8 MiB
  unsigned short* h0 = Wb + (size_t)HID * HID;         // BAT*HID bf16 = 2 MiB
  unsigned short* h1 = h0 + (size_t)BAT * HID;         // 2 MiB

  cvt_kernel<<<dim3((HID * HID) / 1024), 256, 0, stream>>>(whh, Wb, HID * HID);
  hipMemsetAsync(h0, 0, (size_t)BAT * HID * sizeof(unsigned short), stream);

  unsigned short* hin = h0;
  unsigned short* hout = h1;
  for (int t = 0; t < SEQ; ++t) {
    step_kernel<<<dim3(HID / 64, BAT / 64), 256, 0, stream>>>(Wb, hin, hout, whx, bh, x, t);
    unsigned short* tmp = hin; hin = hout; hout = tmp;
  }
  // SEQ even -> final h is in h0 (== hin after last swap)
  proj_kernel<<<dim3(BAT), 256, 0, stream>>>(hin, wp, bp, out);
}

// Round 3
// 2314.811 us; speedup vs baseline: 1.3799x; 1.3799x over previous
//
#include <hip/hip_runtime.h>

#define HID 2048
#define BAT 512
#define SEQ 128
#define NCLS 10

typedef __attribute__((ext_vector_type(4))) float f32x4;
typedef __attribute__((ext_vector_type(8))) short s16x8;
typedef __attribute__((ext_vector_type(4))) unsigned short u16x4;

__device__ __forceinline__ float bf2f(unsigned short u) {
  union { unsigned int i; float f; } v;
  v.i = ((unsigned int)u) << 16;
  return v.f;
}
__device__ __forceinline__ unsigned short f2bf(float f) {
  union { float f; unsigned int i; } v;
  v.f = f;
  unsigned int u = v.i;
  return (unsigned short)((u + 0x7fffu + ((u >> 16) & 1u)) >> 16);
}

// fp32 -> bf16, 4 elems/thread
__global__ __launch_bounds__(256) void cvt_kernel(const float* __restrict__ src,
                                                  unsigned short* __restrict__ dst,
                                                  int n) {
  int i = (blockIdx.x * 256 + threadIdx.x) * 4;
  if (i + 3 < n) {
    f32x4 v = *(const f32x4*)(src + i);
    u16x4 o;
    o.x = f2bf(v.x);
    o.y = f2bf(v.y);
    o.z = f2bf(v.z);
    o.w = f2bf(v.w);
    *(u16x4*)(dst + i) = o;
  }
}

// x[BAT][SEQ] -> xT[SEQ][BAT]  (one-time; coalesced writes)
__global__ __launch_bounds__(256) void xpose_kernel(const float* __restrict__ x,
                                                    float* __restrict__ xT) {
  const int t = blockIdx.x;
  for (int b = threadIdx.x; b < BAT; b += 256)
    xT[t * BAT + b] = x[b * SEQ + t];
}

__device__ __forceinline__ void gload16(const void* g, void* l) {
  __builtin_amdgcn_global_load_lds(
      (const __attribute__((address_space(1))) unsigned int*)g,
      (__attribute__((address_space(3))) unsigned int*)l, 16, 0, 0);
}

// One step: hout[n][m] = tanh( sum_k W[m][k]*hin[n][k] + whx[m]*xT[t][n] + bh[m] )
// Tile BM=64 x BN=64 x BK=64, 512 threads = 8 waves (4m x 2n), wave = 16m x 32n.
// Double-buffered LDS (T3-minimum: prefetch next K-tile, one drain+barrier per K-step).
// T2 chunk-XOR swizzle: LDS tile [64 rows][8 chunks of 16B]; chunk ^= row&7.
// global_load_lds writes linearly -> pre-swizzle the GLOBAL source chunk (involution).
__global__ __launch_bounds__(512) void step_kernel(
    const unsigned short* __restrict__ W,
    const unsigned short* __restrict__ hin,
    unsigned short* __restrict__ hout,
    const float* __restrict__ whx,   // [HID]
    const float* __restrict__ bh,    // [HID]
    const float* __restrict__ xT,    // [SEQ][BAT]
    int t) {
  // [buf][A=0/B=1][64*64]
  __shared__ unsigned short lds[2][2][64 * 64];

  const int tid = threadIdx.x;
  const int wave = tid >> 6;
  const int lane = tid & 63;
  const int m0 = blockIdx.x * 64;
  const int n0 = blockIdx.y * 64;
  const int wm = wave >> 1;   // 0..3
  const int wn = wave & 1;    // 0..1
  const int fl = lane & 15;
  const int hi = lane >> 4;   // 0..3

  // ---- staging geometry: thread t covers linear dest byte t*16 -> row=t>>3, chunk=t&7
  const int srow = tid >> 3;
  const int gchunk = (tid & 7) ^ (srow & 7);  // involution pre-swizzle of source
  const unsigned short* gA = W + (size_t)(m0 + srow) * HID + gchunk * 8;
  const unsigned short* gB = hin + (size_t)(n0 + srow) * HID + gchunk * 8;

  // ---- fragment read offsets (element index within one [64][64] tile)
  // frag element k-base for sub-step ks: ks*32 + hi*8 -> chunk = ks*4 + hi
  const int ra = wm * 16 + fl;        // A row (m-local)
  const int rb0 = wn * 32 + fl;       // B row (n-local), frag 0
  const int rb1 = wn * 32 + 16 + fl;  // B row, frag 1
  int offA[2], offB0[2], offB1[2];
#pragma unroll
  for (int ks = 0; ks < 2; ++ks) {
    const int ch = ks * 4 + hi;
    offA[ks] = ra * 64 + ((ch ^ (ra & 7)) * 8);
    offB0[ks] = rb0 * 64 + ((ch ^ (rb0 & 7)) * 8);
    offB1[ks] = rb1 * 64 + ((ch ^ (rb1 & 7)) * 8);
  }

  f32x4 acc0 = {};
  f32x4 acc1 = {};

  // prologue: stage K-tile 0 into buf 0
  gload16(gA, &lds[0][0][wave * 512]);
  gload16(gB, &lds[0][1][wave * 512]);
  __syncthreads();  // vmcnt(0) + barrier

  int cur = 0;
#pragma unroll 4
  for (int ki = 0; ki < 32; ++ki) {
    if (ki < 31) {  // prefetch next K-tile into the other buffer
      gload16(gA + (ki + 1) * 64, &lds[cur ^ 1][0][wave * 512]);
      gload16(gB + (ki + 1) * 64, &lds[cur ^ 1][1][wave * 512]);
    }
    const unsigned short* LA = lds[cur][0];
    const unsigned short* LB = lds[cur][1];
#pragma unroll
    for (int ks = 0; ks < 2; ++ks) {
      s16x8 a = *(const s16x8*)&LA[offA[ks]];
      s16x8 b0 = *(const s16x8*)&LB[offB0[ks]];
      s16x8 b1 = *(const s16x8*)&LB[offB1[ks]];
      acc0 = __builtin_amdgcn_mfma_f32_16x16x32_bf16(a, b0, acc0, 0, 0, 0);
      acc1 = __builtin_amdgcn_mfma_f32_16x16x32_bf16(a, b1, acc1, 0, 0, 0);
    }
    __syncthreads();  // drains vmcnt (prefetch) + protects both buffers
    cur ^= 1;
  }

  // ---- epilogue: C/D layout col(n)=lane&15, row(m)=hi*4+j  [m89/m91-verified]
  const int mrow = m0 + wm * 16 + hi * 4;
  const f32x4 wx = *(const f32x4*)&whx[mrow];
  const f32x4 bb = *(const f32x4*)&bh[mrow];
  {
    const int ncol = n0 + wn * 32 + fl;
    const float xv = xT[t * BAT + ncol];
    u16x4 o;
#pragma unroll
    for (int j = 0; j < 4; ++j) {
      float z = acc0[j] + wx[j] * xv + bb[j];
      o[j] = f2bf(tanhf(z));
    }
    *(u16x4*)&hout[(size_t)ncol * HID + mrow] = o;
  }
  {
    const int ncol = n0 + wn * 32 + 16 + fl;
    const float xv = xT[t * BAT + ncol];
    u16x4 o;
#pragma unroll
    for (int j = 0; j < 4; ++j) {
      float z = acc1[j] + wx[j] * xv + bb[j];
      o[j] = f2bf(tanhf(z));
    }
    *(u16x4*)&hout[(size_t)ncol * HID + mrow] = o;
  }
}

// out[b][c] = sum_k wp[c][k] * hT[b][k] + bp[c]
__global__ __launch_bounds__(256) void proj_kernel(const unsigned short* __restrict__ hT,
                                                   const float* __restrict__ wp,
                                                   const float* __restrict__ bp,
                                                   float* __restrict__ out) {
  const int b = blockIdx.x;
  const int wave = threadIdx.x >> 6;
  const int lane = threadIdx.x & 63;
  for (int c = wave; c < NCLS; c += 4) {
    float s = 0.f;
    for (int k = lane * 8; k < HID; k += 512) {
      s16x8 hv = *(const s16x8*)&hT[b * HID + k];
      f32x4 w0 = *(const f32x4*)&wp[c * HID + k];
      f32x4 w1 = *(const f32x4*)&wp[c * HID + k + 4];
      s += w0.x * bf2f((unsigned short)hv[0]) + w0.y * bf2f((unsigned short)hv[1]) +
           w0.z * bf2f((unsigned short)hv[2]) + w0.w * bf2f((unsigned short)hv[3]) +
           w1.x * bf2f((unsigned short)hv[4]) + w1.y * bf2f((unsigned short)hv[5]) +
           w1.z * bf2f((unsigned short)hv[6]) + w1.w * bf2f((unsigned short)hv[7]);
    }
#pragma unroll
    for (int off = 32; off > 0; off >>= 1) s += __shfl_down(s, off);
    if (lane == 0) out[b * NCLS + c] = s + bp[c];
  }
}

extern "C" void kernel_launch(void* const* d_in, const int* in_sizes, int n_in,
                              void* d_out, int out_size, void* d_ws, size_t ws_size,
                              hipStream_t stream) {
  (void)in_sizes; (void)n_in; (void)out_size; (void)ws_size;
  const float* x   = (const float*)d_in[0];  // [BAT][SEQ]
  const float* whx = (const float*)d_in[1];  // [HID][1]
  const float* whh = (const float*)d_in[2];  // [HID][HID]
  const float* bh  = (const float*)d_in[3];  // [HID][1]
  const float* wp  = (const float*)d_in[4];  // [NCLS][HID]
  const float* bp  = (const float*)d_in[5];  // [NCLS][1]
  float* out = (float*)d_out;                // [BAT][NCLS]

  unsigned short* Wb = (unsigned short*)d_ws;          // 8 MiB
  unsigned short* h0 = Wb + (size_t)HID * HID;         // 2 MiB
  unsigned short* h1 = h0 + (size_t)BAT * HID;         // 2 MiB
  float* xT = (float*)(h1 + (size_t)BAT * HID);        // 256 KiB

  cvt_kernel<<<dim3((HID * HID) / 1024), 256, 0, stream>>>(whh, Wb, HID * HID);
  xpose_kernel<<<dim3(SEQ), 256, 0, stream>>>(x, xT);
  hipMemsetAsync(h0, 0, (size_t)BAT * HID * sizeof(unsigned short), stream);

  unsigned short* hin = h0;
  unsigned short* hout = h1;
  for (int t = 0; t < SEQ; ++t) {
    step_kernel<<<dim3(HID / 64, BAT / 64), 512, 0, stream>>>(Wb, hin, hout, whx, bh, xT, t);
    unsigned short* tmp = hin; hin = hout; hout = tmp;
  }
  // SEQ even -> final h in h0
  proj_kernel<<<dim3(BAT), 256, 0, stream>>>(hin, wp, bp, out);
}